// Round 6
// baseline (24469.714 us; speedup 1.0000x reference)
//
#include <hip/hip_runtime.h>

// ---------------------------------------------------------------------------
// StackedBLSTMEmbedding: B=32, T=2000, D=80, H=256/dir, HD=512, O=512
// Round 6: unit-split persistent recurrence.
//   r5 lesson: >256 VGPRs spills to scratch (FETCH 65GB). So: 4 blocks per
//   (b,dir), each owns 64 units; thread owns ONE gate-row of Whh in 128 VGPRs
//   (+40 for Wih in layer-1). h exchanged per step between the 4 blocks via
//   agent-scope release/acquire atomics (128B slices through L2/IF).
//   256 blocks on 256 CUs, >=2 blocks/CU capacity -> co-resident; bounded spin.
// ---------------------------------------------------------------------------

typedef _Float16 h2_t __attribute__((ext_vector_type(2)));

__device__ __forceinline__ float dot2acc(unsigned int w, unsigned int h, float acc) {
  h2_t wv = __builtin_bit_cast(h2_t, w);
  h2_t hv = __builtin_bit_cast(h2_t, h);
#if __has_builtin(__builtin_amdgcn_fdot2)
  return __builtin_amdgcn_fdot2(wv, hv, acc, false);
#else
  return acc + (float)wv[0] * (float)hv[0] + (float)wv[1] * (float)hv[1];
#endif
}

__device__ __forceinline__ float dot8(uint4 w, uint4 h, float acc) {
  acc = dot2acc(w.x, h.x, acc);
  acc = dot2acc(w.y, h.y, acc);
  acc = dot2acc(w.z, h.z, acc);
  acc = dot2acc(w.w, h.w, acc);
  return acc;
}

// Pack fp32 W[1024][K] -> f16 uint4 Wp[k8][1024] (k8 = k/8).
__global__ __launch_bounds__(256) void pack_w(const float* __restrict__ W,
                                              uint4* __restrict__ Wp, int K) {
  const int idx = blockIdx.x * 256 + threadIdx.x;
  const int total = (K >> 3) << 10;
  if (idx >= total) return;
  const int g = idx & 1023;
  const int k8 = idx >> 10;
  const float* src = W + (size_t)g * K + k8 * 8;
  h2_t p0, p1, p2, p3;
  p0[0] = (_Float16)src[0]; p0[1] = (_Float16)src[1];
  p1[0] = (_Float16)src[2]; p1[1] = (_Float16)src[3];
  p2[0] = (_Float16)src[4]; p2[1] = (_Float16)src[5];
  p3[0] = (_Float16)src[6]; p3[1] = (_Float16)src[7];
  uint4 o;
  o.x = __builtin_bit_cast(unsigned int, p0);
  o.y = __builtin_bit_cast(unsigned int, p1);
  o.z = __builtin_bit_cast(unsigned int, p2);
  o.w = __builtin_bit_cast(unsigned int, p3);
  Wp[(size_t)k8 * 1024 + g] = o;
}

__global__ __launch_bounds__(256) void pack_flat(const float* __restrict__ src,
                                                 _Float16* __restrict__ dst, int n) {
  const int i = blockIdx.x * 256 + threadIdx.x;
  if (i < n) dst[i] = (_Float16)src[i];
}

__global__ __launch_bounds__(256) void zero16(uint4* __restrict__ p, int n16) {
  const int i = blockIdx.x * 256 + threadIdx.x;
  if (i < n16) { uint4 z; z.x = z.y = z.z = z.w = 0u; p[i] = z; }
}

// C[M][N] = A[M][K](f16) @ B[N][K](f32)^T + bias. M%128==0, N%64==0, K%16==0.
template <typename CT>
__global__ __launch_bounds__(256) void gemm_f16a(
    const _Float16* __restrict__ A, const float* __restrict__ B,
    const float* __restrict__ bias, CT* __restrict__ C,
    int M, int N, int K) {
  __shared__ float As[16][128];
  __shared__ float Bs[16][64];
  const int tid = threadIdx.x;
  const int m0 = blockIdx.y * 128, n0 = blockIdx.x * 64;
  const int ra = tid >> 1;
  const int ca = (tid & 1) * 8;
  const int rb = tid >> 2;
  const int cb = (tid & 3) * 4;
  const int ty = tid >> 4;
  const int tx = tid & 15;
  float acc[8][4] = {};
  for (int k0 = 0; k0 < K; k0 += 16) {
    const uint4 av = *reinterpret_cast<const uint4*>(&A[(size_t)(m0 + ra) * K + k0 + ca]);
    const float4 b0 = *reinterpret_cast<const float4*>(&B[(size_t)(n0 + rb) * K + k0 + cb]);
    __syncthreads();
    {
      h2_t p0 = __builtin_bit_cast(h2_t, av.x);
      h2_t p1 = __builtin_bit_cast(h2_t, av.y);
      h2_t p2 = __builtin_bit_cast(h2_t, av.z);
      h2_t p3 = __builtin_bit_cast(h2_t, av.w);
      As[ca + 0][ra] = (float)p0[0]; As[ca + 1][ra] = (float)p0[1];
      As[ca + 2][ra] = (float)p1[0]; As[ca + 3][ra] = (float)p1[1];
      As[ca + 4][ra] = (float)p2[0]; As[ca + 5][ra] = (float)p2[1];
      As[ca + 6][ra] = (float)p3[0]; As[ca + 7][ra] = (float)p3[1];
    }
    Bs[cb + 0][rb] = b0.x; Bs[cb + 1][rb] = b0.y;
    Bs[cb + 2][rb] = b0.z; Bs[cb + 3][rb] = b0.w;
    __syncthreads();
#pragma unroll
    for (int kk = 0; kk < 16; ++kk) {
      const float4 av0 = *reinterpret_cast<const float4*>(&As[kk][ty * 8]);
      const float4 av1 = *reinterpret_cast<const float4*>(&As[kk][ty * 8 + 4]);
      const float4 bv  = *reinterpret_cast<const float4*>(&Bs[kk][tx * 4]);
      const float a[8] = {av0.x, av0.y, av0.z, av0.w, av1.x, av1.y, av1.z, av1.w};
      const float bb[4] = {bv.x, bv.y, bv.z, bv.w};
#pragma unroll
      for (int i = 0; i < 8; ++i)
#pragma unroll
        for (int j = 0; j < 4; ++j) acc[i][j] += a[i] * bb[j];
    }
  }
  const float4 bias4 = *reinterpret_cast<const float4*>(&bias[n0 + tx * 4]);
  const float bb[4] = {bias4.x, bias4.y, bias4.z, bias4.w};
#pragma unroll
  for (int i = 0; i < 8; ++i) {
    const size_t cidx = (size_t)(m0 + ty * 8 + i) * N + n0 + tx * 4;
    if constexpr (sizeof(CT) == 2) {
      h2_t lo, hi;
      lo[0] = (_Float16)(acc[i][0] + bb[0]); lo[1] = (_Float16)(acc[i][1] + bb[1]);
      hi[0] = (_Float16)(acc[i][2] + bb[2]); hi[1] = (_Float16)(acc[i][3] + bb[3]);
      uint2 st;
      st.x = __builtin_bit_cast(unsigned int, lo);
      st.y = __builtin_bit_cast(unsigned int, hi);
      *reinterpret_cast<uint2*>(&C[cidx]) = st;
    } else {
      float4 o;
      o.x = acc[i][0] + bb[0]; o.y = acc[i][1] + bb[1];
      o.z = acc[i][2] + bb[2]; o.w = acc[i][3] + bb[3];
      *reinterpret_cast<float4*>(&C[cidx]) = o;
    }
  }
}

// ---------------------------------------------------------------------------
// Unit-split persistent recurrence.
// Grid: 256 blocks = 64 groups (b,dir) x 4 sub-blocks. Block sub owns units
// [sub*64, sub*64+64). Thread t: lv=t&63, gate g=t>>6, unit v=sub*64+lv,
// gate-row r=g*256+v. Whh row (32 uint4) + (ONFLY) Wih row (10 uint4) in VGPRs.
// Per step: a = [bias + Wih@x_t | xg] + Whh@h (h broadcast from LDS);
// gates combined via LDS; wave0 threads (t<64) update c,h; h slices exchanged
// between the 4 sub-blocks via agent-scope release/acquire through L2.
// ---------------------------------------------------------------------------
template <int ONFLY, int POOL>
__global__ __launch_bounds__(256) void lstm_ex(
    const _Float16* __restrict__ xg_f, const _Float16* __restrict__ xg_b,
    const uint4* __restrict__ xh,
    const uint4* __restrict__ wih_f, const uint4* __restrict__ wih_b,
    const float* __restrict__ bias_f, const float* __restrict__ bias_b,
    const uint4* __restrict__ whh_f, const uint4* __restrict__ whh_b,
    _Float16* __restrict__ outp, const int* __restrict__ x_len,
    _Float16* __restrict__ exch, unsigned int* __restrict__ flags,
    int lenshift, int T) {
  const int blk = blockIdx.x;
  const int gid = blk >> 2;
  const int sub = blk & 3;
  const int b   = gid >> 1;
  const int dir = gid & 1;
  const int t_  = threadIdx.x;
  const int lv  = t_ & 63;
  const int g   = t_ >> 6;
  const int v   = sub * 64 + lv;
  const int r   = g * 256 + v;
  const int col0 = dir ? 256 : 0;
  const int len = x_len[b] >> lenshift;
  const int Tp = T >> 1;

  const uint4* whh_p = dir ? whh_b : whh_f;
  uint4 wh[32];
#pragma unroll
  for (int k = 0; k < 32; ++k) wh[k] = whh_p[(k << 10) + r];
  uint4 wi[ONFLY ? 10 : 1];
  float bia = 0.f;
  if (ONFLY) {
    const uint4* wih_p = dir ? wih_b : wih_f;
#pragma unroll
    for (int k = 0; k < 10; ++k) wi[k] = wih_p[(k << 10) + r];
    bia = (dir ? bias_b : bias_f)[r];
  }
  const _Float16* xg = dir ? xg_b : xg_f;

  __shared__ __align__(16) _Float16 hbuf[2][256];
  __shared__ float gl[4][64];
  hbuf[0][t_] = (_Float16)0.f;
  hbuf[1][t_] = (_Float16)0.f;
  float c = 0.f, hpend = 0.f;
  __syncthreads();

  int par = 0;
  unsigned int* myflag = flags + ((size_t)gid * 4 + sub) * 16;
  // reader assignment: threads 64..87 pull 3 peers x 8 chunks (16B each)
  const int rj   = (t_ - 64) >> 3;
  const int rck  = (t_ - 64) & 7;
  const int peer = rj + (rj >= sub ? 1 : 0);

  for (int s = 0; s < len; ++s) {
    const int tt = dir ? (len - 1 - s) : s;
    float a;
    if (ONFLY) {
      a = bia;
      const uint4* xr = xh + ((size_t)b * T + tt) * 10;
#pragma unroll
      for (int k = 0; k < 10; ++k) a = dot8(wi[k], xr[k], a);
    } else {
      a = (float)xg[((size_t)b * T + tt) * 1024 + r];
    }
    const uint4* hp = reinterpret_cast<const uint4*>(hbuf[par]);
#pragma unroll
    for (int k = 0; k < 32; ++k) a = dot8(wh[k], hp[k], a);
    gl[g][lv] = a;
    __syncthreads();  // B1: gates ready

    if (t_ < 64) {
      const float ai = gl[0][t_], af = gl[1][t_], agg = gl[2][t_], ao = gl[3][t_];
      const float gi = 1.f / (1.f + expf(-ai));
      const float gf = 1.f / (1.f + expf(-af));
      const float gc = tanhf(agg);
      const float go = 1.f / (1.f + expf(-ao));
      c = gf * c + gi * gc;
      const float h = go * tanhf(c);
      hbuf[par ^ 1][sub * 64 + t_] = (_Float16)h;
      const int v0 = sub * 64 + t_;
      if (POOL) {
        if (dir == 0) {
          if (tt & 1) outp[((size_t)b * Tp + (tt >> 1)) * 512 + col0 + v0] = (_Float16)fmaxf(hpend, h);
          else hpend = h;
        } else {
          if (tt & 1) hpend = h;
          else outp[((size_t)b * Tp + (tt >> 1)) * 512 + col0 + v0] = (_Float16)fmaxf(h, hpend);
        }
      } else {
        outp[((size_t)b * T + tt) * 512 + col0 + v0] = (_Float16)h;
      }
    }
    __syncthreads();  // B2: local h slice in LDS

    // wave 0: publish own slice (plain stores) then release-flag from lane 0.
    // All 8 stores are in wave 0; the release atomic's s_waitcnt+L2-writeback
    // covers the wave's outstanding stores before the flag becomes visible.
    if (t_ < 8) {
      const uint4 pk = *reinterpret_cast<const uint4*>(&hbuf[par ^ 1][sub * 64 + t_ * 8]);
      *reinterpret_cast<uint4*>(
          &exch[((((size_t)gid * 2 + (par ^ 1)) * 4 + sub) * 64) + t_ * 8]) = pk;
    }
    if (t_ == 0) {
      __hip_atomic_store(myflag, (unsigned int)(s + 1), __ATOMIC_RELEASE,
                         __HIP_MEMORY_SCOPE_AGENT);
    }
    // wave 1 (threads 64..87): self-acquire peer flag, then pull peer slice.
    if (t_ >= 64 && t_ < 88) {
      const unsigned int want = (unsigned int)(s + 1);
      unsigned int guard = 0;
      while (__hip_atomic_load(flags + ((size_t)gid * 4 + peer) * 16,
                               __ATOMIC_ACQUIRE, __HIP_MEMORY_SCOPE_AGENT) < want) {
        if (++guard > 0x08000000u) break;  // bounded: avoid hard hang
      }
      const uint4 pk = *reinterpret_cast<const uint4*>(
          &exch[((((size_t)gid * 2 + (par ^ 1)) * 4 + peer) * 64) + rck * 8]);
      *reinterpret_cast<uint4*>(&hbuf[par ^ 1][peer * 64 + rck * 8]) = pk;
    }
    __syncthreads();  // B3: full h ready for next step
    par ^= 1;
  }
  if (POOL && dir == 0 && (len & 1) && t_ < 64) {
    outp[((size_t)b * Tp + ((len - 1) >> 1)) * 512 + col0 + sub * 64 + t_] =
        (_Float16)fmaxf(hpend, 0.f);
  }
}

// r4 streaming recurrence (fallback for tiny workspace), ONFLY only.
template <int ONFLY, int POOL>
__global__ __launch_bounds__(256) void lstm_stream(
    const uint4* __restrict__ xh, int kx8,
    const uint4* __restrict__ wih_f, const uint4* __restrict__ wih_b,
    const float* __restrict__ bias_f, const float* __restrict__ bias_b,
    const uint4* __restrict__ whh_f, const uint4* __restrict__ whh_b,
    _Float16* __restrict__ outp, const int* __restrict__ x_len,
    int lenshift, int T) {
  const int b = blockIdx.x;
  const int dir = blockIdx.y;
  const int u = threadIdx.x;
  const int len = x_len[b] >> lenshift;
  const uint4* wih = dir ? wih_b : wih_f;
  const float* bias = dir ? bias_b : bias_f;
  const uint4* whh0 = (dir ? whh_b : whh_f) + u;
  const int col0 = dir ? 256 : 0;
  const float bi = bias[u], bff = bias[u + 256], bg = bias[u + 512], bo = bias[u + 768];
  __shared__ __align__(16) _Float16 hbuf[2][256];
  hbuf[0][u] = (_Float16)0.f;
  float c = 0.f, hpend = 0.f;
  __syncthreads();
  int cur = 0;
  const int Tp = T >> 1;
  for (int s = 0; s < len; ++s) {
    const int t = dir ? (len - 1 - s) : s;
    float ai = bi, af = bff, ag = bg, ao = bo;
    const uint4* xr = xh + ((size_t)b * T + t) * kx8;
    const uint4* wir = wih + u;
    for (int k8 = 0; k8 < kx8; ++k8) {
      const uint4 xv = xr[k8];
      ai = dot8(wir[0],   xv, ai);
      af = dot8(wir[256], xv, af);
      ag = dot8(wir[512], xv, ag);
      ao = dot8(wir[768], xv, ao);
      wir += 1024;
    }
    const uint4* hp = reinterpret_cast<const uint4*>(hbuf[cur]);
#pragma unroll 4
    for (int k8 = 0; k8 < 32; ++k8) {
      const uint4 hv = hp[k8];
      const uint4* wr = whh0 + (k8 << 10);
      ai = dot8(wr[0],   hv, ai);
      af = dot8(wr[256], hv, af);
      ag = dot8(wr[512], hv, ag);
      ao = dot8(wr[768], hv, ao);
    }
    const float gi = 1.f / (1.f + expf(-ai));
    const float gf = 1.f / (1.f + expf(-af));
    const float gg = tanhf(ag);
    const float go = 1.f / (1.f + expf(-ao));
    c = gf * c + gi * gg;
    const float h = go * tanhf(c);
    if (POOL) {
      if (dir == 0) {
        if (t & 1) outp[((size_t)b * Tp + (t >> 1)) * 512 + col0 + u] = (_Float16)fmaxf(hpend, h);
        else hpend = h;
      } else {
        if (t & 1) hpend = h;
        else outp[((size_t)b * Tp + (t >> 1)) * 512 + col0 + u] = (_Float16)fmaxf(h, hpend);
      }
    } else {
      outp[((size_t)b * T + t) * 512 + col0 + u] = (_Float16)h;
    }
    hbuf[cur ^ 1][u] = (_Float16)h;
    cur ^= 1;
    __syncthreads();
  }
  if (POOL && dir == 0 && (len & 1)) {
    outp[((size_t)b * Tp + ((len - 1) >> 1)) * 512 + col0 + u] = (_Float16)fmaxf(hpend, 0.f);
  }
}

__global__ void lens_k(const int* __restrict__ x_len, float* __restrict__ dst) {
  const int b = threadIdx.x;
  if (b < 32) dst[b] = (float)(x_len[b] >> 1);
}

extern "C" void kernel_launch(void* const* d_in, const int* in_sizes, int n_in,
                              void* d_out, int out_size, void* d_ws, size_t ws_size,
                              hipStream_t stream) {
  (void)in_sizes; (void)n_in; (void)out_size;
  const float* x     = (const float*)d_in[0];
  const int*   x_len = (const int*)d_in[1];
  const float* Wih1f = (const float*)d_in[2];
  const float* Whh1f = (const float*)d_in[3];
  const float* b1f   = (const float*)d_in[4];
  const float* Wih1b = (const float*)d_in[5];
  const float* Whh1b = (const float*)d_in[6];
  const float* b1b   = (const float*)d_in[7];
  const float* Wih2f = (const float*)d_in[8];
  const float* Whh2f = (const float*)d_in[9];
  const float* b2f   = (const float*)d_in[10];
  const float* Wih2b = (const float*)d_in[11];
  const float* Whh2b = (const float*)d_in[12];
  const float* b2b   = (const float*)d_in[13];
  const float* Wlin  = (const float*)d_in[14];
  const float* blin  = (const float*)d_in[15];
  float* outF = (float*)d_out;

  char* w = (char*)d_ws;
  size_t off = 0;
  auto alloc = [&](size_t bytes) -> void* {
    void* p = w + off;
    off += (bytes + 255) & ~(size_t)255;
    return p;
  };
  uint4* wp_hh1f = (uint4*)alloc(524288);
  uint4* wp_hh1b = (uint4*)alloc(524288);
  uint4* wp_hh2f = (uint4*)alloc(524288);
  uint4* wp_hh2b = (uint4*)alloc(524288);
  uint4* wp_ih1f = (uint4*)alloc(163840);
  uint4* wp_ih1b = (uint4*)alloc(163840);
  uint4* wp_ih2f = (uint4*)alloc(1048576);
  uint4* wp_ih2b = (uint4*)alloc(1048576);
  _Float16* x_h    = (_Float16*)alloc(10240000);   // 32*2000*80 f16
  _Float16* pooled = (_Float16*)alloc(32768000);   // 32*1000*512 f16
  _Float16* out2   = (_Float16*)alloc(32768000);   // 32*1000*512 f16 (contiguous)
  _Float16* exch1  = (_Float16*)alloc(65536);      // 64*2*4*64 f16
  _Float16* exch2  = (_Float16*)alloc(65536);
  unsigned int* flags1 = (unsigned int*)alloc(16384);  // 64*4 u32, 64B stride
  unsigned int* flags2 = (unsigned int*)alloc(16384);
  const size_t var_off = off;
  _Float16* varr = (_Float16*)(w + var_off);
  _Float16* xg2f = varr;                  // 32*1000*1024 f16 = 65,536,000 B
  _Float16* xg2b = varr + 32768000;

  const int tier1 = (ws_size >= var_off + 131072000ULL) ? 1 : 0;

  // Pack weights + input
  pack_w<<<128, 256, 0, stream>>>(Whh1f, wp_hh1f, 256);
  pack_w<<<128, 256, 0, stream>>>(Whh1b, wp_hh1b, 256);
  pack_w<<<128, 256, 0, stream>>>(Whh2f, wp_hh2f, 256);
  pack_w<<<128, 256, 0, stream>>>(Whh2b, wp_hh2b, 256);
  pack_w<<<40, 256, 0, stream>>>(Wih1f, wp_ih1f, 80);
  pack_w<<<40, 256, 0, stream>>>(Wih1b, wp_ih1b, 80);
  pack_w<<<256, 256, 0, stream>>>(Wih2f, wp_ih2f, 512);
  pack_w<<<256, 256, 0, stream>>>(Wih2b, wp_ih2b, 512);
  pack_flat<<<20000, 256, 0, stream>>>(x, x_h, 5120000);
  // zero pooled+out2 (contiguous) and exch/flags (contiguous)
  zero16<<<16000, 256, 0, stream>>>((uint4*)pooled, 4096000);
  zero16<<<40, 256, 0, stream>>>((uint4*)exch1, 10240);

  // ---- Layer 1: unit-split, ONFLY, fused pool ----
  lstm_ex<1, 1><<<256, 256, 0, stream>>>(
      nullptr, nullptr, (const uint4*)x_h,
      wp_ih1f, wp_ih1b, b1f, b1b, wp_hh1f, wp_hh1b,
      pooled, x_len, exch1, flags1, 0, 2000);

  // ---- Layer 2 ----
  if (tier1) {
    gemm_f16a<_Float16><<<dim3(16, 250), 256, 0, stream>>>(pooled, Wih2f, b2f, xg2f, 32000, 1024, 512);
    gemm_f16a<_Float16><<<dim3(16, 250), 256, 0, stream>>>(pooled, Wih2b, b2b, xg2b, 32000, 1024, 512);
    lstm_ex<0, 0><<<256, 256, 0, stream>>>(
        xg2f, xg2b, nullptr,
        nullptr, nullptr, nullptr, nullptr, wp_hh2f, wp_hh2b,
        out2, x_len, exch2, flags2, 1, 1000);
  } else {
    lstm_stream<1, 0><<<dim3(32, 2), 256, 0, stream>>>(
        (const uint4*)pooled, 64, wp_ih2f, wp_ih2b, b2f, b2b,
        wp_hh2f, wp_hh2b, out2, x_len, 1, 1000);
  }

  // ---- Final linear + lens ----
  gemm_f16a<float><<<dim3(8, 250), 256, 0, stream>>>(out2, Wlin, blin, outF, 32000, 512, 512);
  lens_k<<<1, 32, 0, stream>>>(x_len, outF + (size_t)16384000);
}

// Round 7
// 9008.041 us; speedup vs baseline: 2.7164x; 2.7164x over previous
//
#include <hip/hip_runtime.h>

// ---------------------------------------------------------------------------
// StackedBLSTMEmbedding: B=32, T=2000, D=80, H=256/dir, HD=512, O=512
// Round 7: fully on-chip Whh via VGPR(10ch) + AGPR(15ch, inline-asm parked)
//          + LDS(7ch). No per-step streaming, no cross-CU sync (r6 lesson),
//          no >256-VGPR ambition (r5 lesson). Layer-1 xg precomputed in
//          4x500-step windows (fits ws); bwd reversal folded into gemm A-row
//          mapping. State (h,c,hpend) carried through ws between windows.
// ---------------------------------------------------------------------------

typedef _Float16 h2_t __attribute__((ext_vector_type(2)));

constexpr int RC = 10;   // Whh chunks in VGPRs (40 uint4 = 160 regs)
constexpr int AC = 15;   // Whh chunks in AGPRs (60 uint4 = 240 AGPRs)
constexpr int LC = 7;    // Whh chunks in LDS (114,688 B)

__device__ __forceinline__ float dot2acc(unsigned int w, unsigned int h, float acc) {
  h2_t wv = __builtin_bit_cast(h2_t, w);
  h2_t hv = __builtin_bit_cast(h2_t, h);
#if __has_builtin(__builtin_amdgcn_fdot2)
  return __builtin_amdgcn_fdot2(wv, hv, acc, false);
#else
  return acc + (float)wv[0] * (float)hv[0] + (float)wv[1] * (float)hv[1];
#endif
}

__device__ __forceinline__ float dot8(uint4 w, uint4 h, float acc) {
  acc = dot2acc(w.x, h.x, acc);
  acc = dot2acc(w.y, h.y, acc);
  acc = dot2acc(w.z, h.z, acc);
  acc = dot2acc(w.w, h.w, acc);
  return acc;
}

__device__ __forceinline__ float sigf(float x) { return 1.f / (1.f + __expf(-x)); }

// Pack fp32 W[1024][K] -> f16 uint4 Wp[k8][1024] (k8 = k/8).
__global__ __launch_bounds__(256) void pack_w(const float* __restrict__ W,
                                              uint4* __restrict__ Wp, int K) {
  const int idx = blockIdx.x * 256 + threadIdx.x;
  const int total = (K >> 3) << 10;
  if (idx >= total) return;
  const int g = idx & 1023;
  const int k8 = idx >> 10;
  const float* src = W + (size_t)g * K + k8 * 8;
  h2_t p0, p1, p2, p3;
  p0[0] = (_Float16)src[0]; p0[1] = (_Float16)src[1];
  p1[0] = (_Float16)src[2]; p1[1] = (_Float16)src[3];
  p2[0] = (_Float16)src[4]; p2[1] = (_Float16)src[5];
  p3[0] = (_Float16)src[6]; p3[1] = (_Float16)src[7];
  uint4 o;
  o.x = __builtin_bit_cast(unsigned int, p0);
  o.y = __builtin_bit_cast(unsigned int, p1);
  o.z = __builtin_bit_cast(unsigned int, p2);
  o.w = __builtin_bit_cast(unsigned int, p3);
  Wp[(size_t)k8 * 1024 + g] = o;
}

__global__ __launch_bounds__(256) void pack_flat(const float* __restrict__ src,
                                                 _Float16* __restrict__ dst, int n) {
  const int i = blockIdx.x * 256 + threadIdx.x;
  if (i < n) dst[i] = (_Float16)src[i];
}

__global__ __launch_bounds__(256) void zero16(uint4* __restrict__ p, int n16) {
  const int i = blockIdx.x * 256 + threadIdx.x;
  if (i < n16) { uint4 z; z.x = z.y = z.z = z.w = 0u; p[i] = z; }
}

// C[M][N] = A'[M][K] @ B[N][K]^T + bias.  M%128==0, N%64==0, K%16==0.
// Window remap (Twin>0): row m -> b=m/Twin, ti=t0+m%Twin; REV: ti=len_b-1-ti
// (clamped); A-row = b*Tfull+ti. Twin==0: identity.
template <typename AT, typename CT>
__global__ __launch_bounds__(256) void gemm_any(
    const AT* __restrict__ A, const float* __restrict__ B,
    const float* __restrict__ bias, CT* __restrict__ C,
    int M, int N, int K, int Twin, int Tfull, int t0, int REV,
    const int* __restrict__ x_len, int lensh) {
  __shared__ float As[16][128];
  __shared__ float Bs[16][64];
  const int tid = threadIdx.x;
  const int m0 = blockIdx.y * 128, n0 = blockIdx.x * 64;
  const int ra = tid >> 1;
  const int ca = (tid & 1) * 8;
  const int rb = tid >> 2;
  const int cb = (tid & 3) * 4;
  const int ty = tid >> 4;
  const int tx = tid & 15;
  const int am = m0 + ra;
  int arow = am;
  if (Twin > 0) {
    const int bb = am / Twin;
    int ti = t0 + (am - bb * Twin);
    if (REV) {
      const int L = x_len[bb] >> lensh;
      ti = L - 1 - ti;
      ti = ti < 0 ? 0 : ti;
    }
    arow = bb * Tfull + ti;
  }
  float acc[8][4] = {};
  for (int k0 = 0; k0 < K; k0 += 16) {
    float a8[8];
    if constexpr (sizeof(AT) == 2) {
      const uint4 av = *reinterpret_cast<const uint4*>(&A[(size_t)arow * K + k0 + ca]);
      h2_t p0 = __builtin_bit_cast(h2_t, av.x);
      h2_t p1 = __builtin_bit_cast(h2_t, av.y);
      h2_t p2 = __builtin_bit_cast(h2_t, av.z);
      h2_t p3 = __builtin_bit_cast(h2_t, av.w);
      a8[0] = (float)p0[0]; a8[1] = (float)p0[1];
      a8[2] = (float)p1[0]; a8[3] = (float)p1[1];
      a8[4] = (float)p2[0]; a8[5] = (float)p2[1];
      a8[6] = (float)p3[0]; a8[7] = (float)p3[1];
    } else {
      const float4 a0 = *reinterpret_cast<const float4*>(&A[(size_t)arow * K + k0 + ca]);
      const float4 a1 = *reinterpret_cast<const float4*>(&A[(size_t)arow * K + k0 + ca + 4]);
      a8[0] = a0.x; a8[1] = a0.y; a8[2] = a0.z; a8[3] = a0.w;
      a8[4] = a1.x; a8[5] = a1.y; a8[6] = a1.z; a8[7] = a1.w;
    }
    const float4 b0 = *reinterpret_cast<const float4*>(&B[(size_t)(n0 + rb) * K + k0 + cb]);
    __syncthreads();
#pragma unroll
    for (int q = 0; q < 8; ++q) As[ca + q][ra] = a8[q];
    Bs[cb + 0][rb] = b0.x; Bs[cb + 1][rb] = b0.y;
    Bs[cb + 2][rb] = b0.z; Bs[cb + 3][rb] = b0.w;
    __syncthreads();
#pragma unroll
    for (int kk = 0; kk < 16; ++kk) {
      const float4 av0 = *reinterpret_cast<const float4*>(&As[kk][ty * 8]);
      const float4 av1 = *reinterpret_cast<const float4*>(&As[kk][ty * 8 + 4]);
      const float4 bv  = *reinterpret_cast<const float4*>(&Bs[kk][tx * 4]);
      const float a[8] = {av0.x, av0.y, av0.z, av0.w, av1.x, av1.y, av1.z, av1.w};
      const float bb4[4] = {bv.x, bv.y, bv.z, bv.w};
#pragma unroll
      for (int i = 0; i < 8; ++i)
#pragma unroll
        for (int j = 0; j < 4; ++j) acc[i][j] += a[i] * bb4[j];
    }
  }
  const float4 bias4 = *reinterpret_cast<const float4*>(&bias[n0 + tx * 4]);
  const float bb4[4] = {bias4.x, bias4.y, bias4.z, bias4.w};
#pragma unroll
  for (int i = 0; i < 8; ++i) {
    const size_t cidx = (size_t)(m0 + ty * 8 + i) * N + n0 + tx * 4;
    if constexpr (sizeof(CT) == 2) {
      h2_t lo, hi;
      lo[0] = (_Float16)(acc[i][0] + bb4[0]); lo[1] = (_Float16)(acc[i][1] + bb4[1]);
      hi[0] = (_Float16)(acc[i][2] + bb4[2]); hi[1] = (_Float16)(acc[i][3] + bb4[3]);
      uint2 st;
      st.x = __builtin_bit_cast(unsigned int, lo);
      st.y = __builtin_bit_cast(unsigned int, hi);
      *reinterpret_cast<uint2*>(&C[cidx]) = st;
    } else {
      float4 o;
      o.x = acc[i][0] + bb4[0]; o.y = acc[i][1] + bb4[1];
      o.z = acc[i][2] + bb4[2]; o.w = acc[i][3] + bb4[3];
      *reinterpret_cast<float4*>(&C[cidx]) = o;
    }
  }
}

// ---------------------------------------------------------------------------
// On-chip recurrence. 1 block per (b,dir), 256 threads; thread u owns unit u
// (gate rows u,u+256,u+512,u+768). Whh: RC chunks VGPR, AC chunks AGPR
// (explicit v_accvgpr park), LC chunks LDS. xg precomputed (window buffer
// [b][Twin][1024], bias included; bwd already time-reversed). One barrier/step.
// ---------------------------------------------------------------------------
#define AWR(i, src) asm volatile("v_accvgpr_write_b32 %0, %1" : "=a"(agw[i]) : "v"(src))
#define ARD(dst, i) asm volatile("v_accvgpr_read_b32 %0, %1" : "=v"(dst) : "a"(agw[i]))

template <int POOL>
__global__ __launch_bounds__(256, 1) void lstm_oc(
    const _Float16* __restrict__ xgF, const _Float16* __restrict__ xgB,
    const uint4* __restrict__ whhF, const uint4* __restrict__ whhB,
    _Float16* __restrict__ outp, const int* __restrict__ x_len,
    float* __restrict__ stC, _Float16* __restrict__ stH, float* __restrict__ stP,
    int lenshift, int T, int Twin, int s0) {
  const int b = blockIdx.x;
  const int dir = blockIdx.y;
  const int u = threadIdx.x;
  const int len = x_len[b] >> lenshift;
  if (s0 >= len) return;                  // block-uniform: no work this window
  const int ns = min(Twin, len - s0);
  const int col0 = dir ? 256 : 0;
  const int Tp = T >> 1;
  const int sidx = (b * 2 + dir) * 256 + u;
  const uint4* whh0 = (dir ? whhB : whhF) + u;
  const _Float16* xg = dir ? xgB : xgF;

  // VGPR-resident chunks 0..RC-1
  uint4 wreg[RC][4];
#pragma unroll
  for (int k = 0; k < RC; ++k)
#pragma unroll
    for (int g = 0; g < 4; ++g) wreg[k][g] = whh0[(k << 10) + (g << 8)];

  // AGPR-parked chunks RC..RC+AC-1
  unsigned agw[AC * 16];
#pragma unroll
  for (int k = 0; k < AC; ++k) {
#pragma unroll
    for (int g = 0; g < 4; ++g) {
      const uint4 w = whh0[((RC + k) << 10) + (g << 8)];
      const int base = (k * 4 + g) * 4;
      AWR(base + 0, w.x);
      AWR(base + 1, w.y);
      AWR(base + 2, w.z);
      AWR(base + 3, w.w);
    }
  }

  // LDS-resident chunks RC+AC..31
  __shared__ uint4 wlds[LC][4][256];
  __shared__ __align__(16) _Float16 hb[2][256];
#pragma unroll
  for (int lc = 0; lc < LC; ++lc)
#pragma unroll
    for (int g = 0; g < 4; ++g) wlds[lc][g][u] = whh0[((RC + AC + lc) << 10) + (g << 8)];

  hb[0][u] = stH[sidx];
  float c = stC[sidx];
  float hpend = stP[sidx];
  __syncthreads();

  int par = 0;
  for (int j = 0; j < ns; ++j) {
    const int s = s0 + j;
    const int t = dir ? (len - 1 - s) : s;
    // xg loads issued early; folded into accumulators at the end (hides L2 lat)
    const _Float16* xp = xg + ((size_t)b * Twin + j) * 1024 + u;
    const float xi = (float)xp[0];
    const float xf = (float)xp[256];
    const float xgg = (float)xp[512];
    const float xo = (float)xp[768];
    float ai = 0.f, af = 0.f, ag = 0.f, ao = 0.f;
    const uint4* hp = reinterpret_cast<const uint4*>(hb[par]);
#pragma unroll
    for (int k = 0; k < RC; ++k) {
      const uint4 hv = hp[k];
      ai = dot8(wreg[k][0], hv, ai);
      af = dot8(wreg[k][1], hv, af);
      ag = dot8(wreg[k][2], hv, ag);
      ao = dot8(wreg[k][3], hv, ao);
    }
#pragma unroll
    for (int k = 0; k < AC; ++k) {
      const uint4 hv = hp[RC + k];
#pragma unroll
      for (int g = 0; g < 4; ++g) {
        uint4 w;
        const int base = (k * 4 + g) * 4;
        ARD(w.x, base + 0);
        ARD(w.y, base + 1);
        ARD(w.z, base + 2);
        ARD(w.w, base + 3);
        if (g == 0) ai = dot8(w, hv, ai);
        else if (g == 1) af = dot8(w, hv, af);
        else if (g == 2) ag = dot8(w, hv, ag);
        else ao = dot8(w, hv, ao);
      }
    }
#pragma unroll
    for (int lc = 0; lc < LC; ++lc) {
      const uint4 hv = hp[RC + AC + lc];
      ai = dot8(wlds[lc][0][u], hv, ai);
      af = dot8(wlds[lc][1][u], hv, af);
      ag = dot8(wlds[lc][2][u], hv, ag);
      ao = dot8(wlds[lc][3][u], hv, ao);
    }
    ai += xi; af += xf; ag += xgg; ao += xo;
    const float gi = sigf(ai);
    const float gf = sigf(af);
    const float gc = 2.f * sigf(2.f * ag) - 1.f;
    const float go = sigf(ao);
    c = gf * c + gi * gc;
    const float h = go * (2.f * sigf(2.f * c) - 1.f);
    if (POOL) {
      if (dir == 0) {
        if (t & 1) outp[((size_t)b * Tp + (t >> 1)) * 512 + col0 + u] = (_Float16)fmaxf(hpend, h);
        else hpend = h;
      } else {
        if (t & 1) hpend = h;
        else outp[((size_t)b * Tp + (t >> 1)) * 512 + col0 + u] = (_Float16)fmaxf(h, hpend);
      }
    } else {
      outp[((size_t)b * T + t) * 512 + col0 + u] = (_Float16)h;
    }
    hb[par ^ 1][u] = (_Float16)h;
    par ^= 1;
    __syncthreads();
  }
  // save state for next window
  stH[sidx] = hb[par][u];
  stC[sidx] = c;
  stP[sidx] = hpend;
  // pooled tail (odd len, fwd): only in the window where len ends
  if (POOL && dir == 0 && (len & 1) && (len - s0) <= Twin) {
    outp[((size_t)b * Tp + ((len - 1) >> 1)) * 512 + col0 + u] = (_Float16)fmaxf(hpend, 0.f);
  }
}

// r4-style streaming recurrence (fallback for small workspace), ONFLY.
template <int POOL>
__global__ __launch_bounds__(256) void lstm_stream(
    const uint4* __restrict__ xh, int kx8,
    const uint4* __restrict__ wih_f, const uint4* __restrict__ wih_b,
    const float* __restrict__ bias_f, const float* __restrict__ bias_b,
    const uint4* __restrict__ whh_f, const uint4* __restrict__ whh_b,
    _Float16* __restrict__ outp, const int* __restrict__ x_len,
    int lenshift, int T) {
  const int b = blockIdx.x;
  const int dir = blockIdx.y;
  const int u = threadIdx.x;
  const int len = x_len[b] >> lenshift;
  const uint4* wih = dir ? wih_b : wih_f;
  const float* bias = dir ? bias_b : bias_f;
  const uint4* whh0 = (dir ? whh_b : whh_f) + u;
  const int col0 = dir ? 256 : 0;
  const float bi = bias[u], bff = bias[u + 256], bg = bias[u + 512], bo = bias[u + 768];
  __shared__ __align__(16) _Float16 hbuf[2][256];
  hbuf[0][u] = (_Float16)0.f;
  float c = 0.f, hpend = 0.f;
  __syncthreads();
  int cur = 0;
  const int Tp = T >> 1;
  for (int s = 0; s < len; ++s) {
    const int t = dir ? (len - 1 - s) : s;
    float ai = bi, af = bff, ag = bg, ao = bo;
    const uint4* xr = xh + ((size_t)b * T + t) * kx8;
    const uint4* wir = wih + u;
    for (int k8 = 0; k8 < kx8; ++k8) {
      const uint4 xv = xr[k8];
      ai = dot8(wir[0],   xv, ai);
      af = dot8(wir[256], xv, af);
      ag = dot8(wir[512], xv, ag);
      ao = dot8(wir[768], xv, ao);
      wir += 1024;
    }
    const uint4* hp = reinterpret_cast<const uint4*>(hbuf[cur]);
#pragma unroll 4
    for (int k8 = 0; k8 < 32; ++k8) {
      const uint4 hv = hp[k8];
      const uint4* wr = whh0 + (k8 << 10);
      ai = dot8(wr[0],   hv, ai);
      af = dot8(wr[256], hv, af);
      ag = dot8(wr[512], hv, ag);
      ao = dot8(wr[768], hv, ao);
    }
    const float gi = sigf(ai);
    const float gf = sigf(af);
    const float gg = 2.f * sigf(2.f * ag) - 1.f;
    const float go = sigf(ao);
    c = gf * c + gi * gg;
    const float h = go * (2.f * sigf(2.f * c) - 1.f);
    if (POOL) {
      if (dir == 0) {
        if (t & 1) outp[((size_t)b * Tp + (t >> 1)) * 512 + col0 + u] = (_Float16)fmaxf(hpend, h);
        else hpend = h;
      } else {
        if (t & 1) hpend = h;
        else outp[((size_t)b * Tp + (t >> 1)) * 512 + col0 + u] = (_Float16)fmaxf(h, hpend);
      }
    } else {
      outp[((size_t)b * T + t) * 512 + col0 + u] = (_Float16)h;
    }
    hbuf[cur ^ 1][u] = (_Float16)h;
    cur ^= 1;
    __syncthreads();
  }
  if (POOL && dir == 0 && (len & 1)) {
    outp[((size_t)b * Tp + ((len - 1) >> 1)) * 512 + col0 + u] = (_Float16)fmaxf(hpend, 0.f);
  }
}

__global__ void lens_k(const int* __restrict__ x_len, float* __restrict__ dst) {
  const int b = threadIdx.x;
  if (b < 32) dst[b] = (float)(x_len[b] >> 1);
}

extern "C" void kernel_launch(void* const* d_in, const int* in_sizes, int n_in,
                              void* d_out, int out_size, void* d_ws, size_t ws_size,
                              hipStream_t stream) {
  (void)in_sizes; (void)n_in; (void)out_size;
  const float* x     = (const float*)d_in[0];
  const int*   x_len = (const int*)d_in[1];
  const float* Wih1f = (const float*)d_in[2];
  const float* Whh1f = (const float*)d_in[3];
  const float* b1f   = (const float*)d_in[4];
  const float* Wih1b = (const float*)d_in[5];
  const float* Whh1b = (const float*)d_in[6];
  const float* b1b   = (const float*)d_in[7];
  const float* Wih2f = (const float*)d_in[8];
  const float* Whh2f = (const float*)d_in[9];
  const float* b2f   = (const float*)d_in[10];
  const float* Wih2b = (const float*)d_in[11];
  const float* Whh2b = (const float*)d_in[12];
  const float* b2b   = (const float*)d_in[13];
  const float* Wlin  = (const float*)d_in[14];
  const float* blin  = (const float*)d_in[15];
  float* outF = (float*)d_out;

  char* w = (char*)d_ws;
  size_t off = 0;
  auto alloc = [&](size_t bytes) -> void* {
    void* p = w + off;
    off += (bytes + 255) & ~(size_t)255;
    return p;
  };
  uint4* wp_hh1f = (uint4*)alloc(524288);
  uint4* wp_hh1b = (uint4*)alloc(524288);
  uint4* wp_hh2f = (uint4*)alloc(524288);
  uint4* wp_hh2b = (uint4*)alloc(524288);
  uint4* wp_ih1f = (uint4*)alloc(163840);      // fallback only
  uint4* wp_ih1b = (uint4*)alloc(163840);
  uint4* wp_ih2f = (uint4*)alloc(1048576);
  uint4* wp_ih2b = (uint4*)alloc(1048576);
  _Float16* pooled = (_Float16*)alloc(32768000);  // [32][1000][512] f16
  _Float16* out2   = (_Float16*)alloc(32768000);  // [32][1000][512] f16 (contiguous)
  float*    stC1 = (float*)alloc(65536);          // states, contiguous block
  _Float16* stH1 = (_Float16*)alloc(32768);
  float*    stP1 = (float*)alloc(65536);
  float*    stC2 = (float*)alloc(65536);
  _Float16* stH2 = (_Float16*)alloc(32768);
  float*    stP2 = (float*)alloc(65536);
  const size_t var_off = off;
  _Float16* varr = (_Float16*)(w + var_off);
  _Float16* xgwF = varr;                 // [32][500][1024] f16 = 32,768,000 B
  _Float16* xgwB = varr + 16384000;
  _Float16* xg2f = varr;                 // [32][1000][1024] f16 = 65,536,000 B
  _Float16* xg2b = varr + 32768000;
  _Float16* x_h  = varr;                 // fallback: [32][2000][80] f16

  const int main_tier = (ws_size >= var_off + 131072000ULL) ? 1 : 0;

  // Whh packs (always)
  pack_w<<<128, 256, 0, stream>>>(Whh1f, wp_hh1f, 256);
  pack_w<<<128, 256, 0, stream>>>(Whh1b, wp_hh1b, 256);
  pack_w<<<128, 256, 0, stream>>>(Whh2f, wp_hh2f, 256);
  pack_w<<<128, 256, 0, stream>>>(Whh2b, wp_hh2b, 256);
  // zero pooled+out2 (contiguous) and all state buffers (contiguous)
  zero16<<<16000, 256, 0, stream>>>((uint4*)pooled, 4096000);
  zero16<<<80, 256, 0, stream>>>((uint4*)stC1, 20480);

  if (main_tier) {
    // ---- Layer 1: 4 windows of 500 steps ----
    for (int w4 = 0; w4 < 4; ++w4) {
      const int t0 = 500 * w4;
      gemm_any<float, _Float16><<<dim3(16, 125), 256, 0, stream>>>(
          x, Wih1f, b1f, xgwF, 16000, 1024, 80, 500, 2000, t0, 0, x_len, 0);
      gemm_any<float, _Float16><<<dim3(16, 125), 256, 0, stream>>>(
          x, Wih1b, b1b, xgwB, 16000, 1024, 80, 500, 2000, t0, 1, x_len, 0);
      lstm_oc<1><<<dim3(32, 2), 256, 0, stream>>>(
          xgwF, xgwB, wp_hh1f, wp_hh1b, pooled, x_len,
          stC1, stH1, stP1, 0, 2000, 500, t0);
    }
    // ---- Layer 2 ----
    gemm_any<_Float16, _Float16><<<dim3(16, 250), 256, 0, stream>>>(
        pooled, Wih2f, b2f, xg2f, 32000, 1024, 512, 0, 0, 0, 0, nullptr, 0);
    gemm_any<_Float16, _Float16><<<dim3(16, 250), 256, 0, stream>>>(
        pooled, Wih2b, b2b, xg2b, 32000, 1024, 512, 0, 0, 0, 0, nullptr, 0);
    lstm_oc<0><<<dim3(32, 2), 256, 0, stream>>>(
        xg2f, xg2b, wp_hh2f, wp_hh2b, out2, x_len,
        stC2, stH2, stP2, 1, 1000, 1000, 0);
  } else {
    // ---- Fallback (r4-proven): ONFLY streaming both layers ----
    pack_w<<<40, 256, 0, stream>>>(Wih1f, wp_ih1f, 80);
    pack_w<<<40, 256, 0, stream>>>(Wih1b, wp_ih1b, 80);
    pack_w<<<256, 256, 0, stream>>>(Wih2f, wp_ih2f, 512);
    pack_w<<<256, 256, 0, stream>>>(Wih2b, wp_ih2b, 512);
    pack_flat<<<20000, 256, 0, stream>>>(x, x_h, 5120000);
    lstm_stream<1><<<dim3(32, 2), 256, 0, stream>>>(
        (const uint4*)x_h, 10, wp_ih1f, wp_ih1b, b1f, b1b,
        wp_hh1f, wp_hh1b, pooled, x_len, 0, 2000);
    lstm_stream<0><<<dim3(32, 2), 256, 0, stream>>>(
        (const uint4*)pooled, 64, wp_ih2f, wp_ih2b, b2f, b2b,
        wp_hh2f, wp_hh2b, out2, x_len, 1, 1000);
  }

  // ---- Final linear + lens ----
  gemm_any<_Float16, float><<<dim3(8, 250), 256, 0, stream>>>(
      out2, Wlin, blin, outF, 32000, 512, 512, 0, 0, 0, 0, nullptr, 0);
  lens_k<<<1, 32, 0, stream>>>(x_len, outF + (size_t)16384000);
}